// Round 1
// baseline (122.675 us; speedup 1.0000x reference)
//
#include <hip/hip_runtime.h>
#include <hip/hip_bf16.h>

// BallQueryAttention on MI355X.
// out_i = (S_ball_i + K*(S_total - S_ball_i)) / (c_i + K*(N - c_i)), K = exp(-1)
// S_ball_i = sum of x_j with ||x_i-x_j||^2 <= 121, computed via MFMA:
//   d2 = sq_i + sq_j - 2*dot, dot via split-bf16 (hi*hi + hi*lo + lo*hi)
//   S_ball = mask @ x_hi  (bf16 0/1 mask, MFMA)

#define NROWS 8192
#define DDIM  64

typedef __bf16 bf16x8 __attribute__((ext_vector_type(8)));
typedef float  f32x4  __attribute__((ext_vector_type(4)));

#define MFMA16(A, B, C) __builtin_amdgcn_mfma_f32_16x16x32_bf16((A), (B), (C), 0, 0, 0)

static __device__ __forceinline__ unsigned short bf16rn(float f) {
    unsigned u = __float_as_uint(f);
    unsigned r = u + 0x7FFFu + ((u >> 16) & 1u);
    return (unsigned short)(r >> 16);
}
static __device__ __forceinline__ float bf16tof(unsigned short h) {
    return __uint_as_float(((unsigned)h) << 16);
}

// ---------------- prep: hi/lo bf16 split + row sq-norms -------------------
__global__ __launch_bounds__(256) void prep_hilo(const float* __restrict__ x,
                                                 unsigned short* __restrict__ xhi,
                                                 unsigned short* __restrict__ xlo,
                                                 float* __restrict__ sq) {
    int t = blockIdx.x * 256 + threadIdx.x;   // 131072 threads, 4 elems each
    int row = t >> 4, q = t & 15;
    const float4 v = *(const float4*)(x + ((size_t)row << 6) + (q << 2));
    float f0 = v.x, f1 = v.y, f2 = v.z, f3 = v.w;
    unsigned short h0 = bf16rn(f0), h1 = bf16rn(f1), h2 = bf16rn(f2), h3 = bf16rn(f3);
    unsigned short l0 = bf16rn(f0 - bf16tof(h0));
    unsigned short l1 = bf16rn(f1 - bf16tof(h1));
    unsigned short l2 = bf16rn(f2 - bf16tof(h2));
    unsigned short l3 = bf16rn(f3 - bf16tof(h3));
    float ss = f0 * f0;
    ss = fmaf(f1, f1, ss); ss = fmaf(f2, f2, ss); ss = fmaf(f3, f3, ss);
    uint2 ph, pl;
    ph.x = (unsigned)h0 | ((unsigned)h1 << 16);
    ph.y = (unsigned)h2 | ((unsigned)h3 << 16);
    pl.x = (unsigned)l0 | ((unsigned)l1 << 16);
    pl.y = (unsigned)l2 | ((unsigned)l3 << 16);
    *(uint2*)(xhi + ((size_t)row << 6) + (q << 2)) = ph;
    *(uint2*)(xlo + ((size_t)row << 6) + (q << 2)) = pl;
    // reduce sq over the 16 lanes that share this row (q = lane&15)
    ss += __shfl_xor(ss, 1);
    ss += __shfl_xor(ss, 2);
    ss += __shfl_xor(ss, 4);
    ss += __shfl_xor(ss, 8);
    if (q == 0) sq[row] = ss;
}

// ---------------- prep: column totals S_total ------------------------------
__global__ __launch_bounds__(256) void prep_coltot(const float* __restrict__ x,
                                                   float* __restrict__ stot) {
    __shared__ float red[4][64];
    int g = blockIdx.x;                       // 64 blocks, 128 rows each
    int col = threadIdx.x & 63, rg = threadIdx.x >> 6;
    float s = 0.f;
    int base = g * 128 + rg;
    for (int k = 0; k < 32; ++k)
        s += x[(size_t)(base + 4 * k) * 64 + col];
    red[rg][col] = s;
    __syncthreads();
    if (threadIdx.x < 64) {
        float v = red[0][threadIdx.x] + red[1][threadIdx.x] +
                  red[2][threadIdx.x] + red[3][threadIdx.x];
        atomicAdd(stot + threadIdx.x, v);
    }
}

// ---------------- main fused kernel ---------------------------------------
// grid = 64 i-tiles (BI=128) x nchunk j-chunks; 256 threads (4 waves, 2x2).
__global__ __launch_bounds__(256, 2) void ballq_main(
        const unsigned short* __restrict__ xhi,
        const unsigned short* __restrict__ xlo,
        const float* __restrict__ sq,
        float* __restrict__ Spart, float* __restrict__ cpart, int nchunk) {
    __shared__ unsigned short sJhi[64][72];   // [j][d]  row-major, pad->144B stride
    __shared__ unsigned short sJlo[64][72];
    __shared__ unsigned short sJT [64][72];   // [d][j]  transposed hi
    __shared__ unsigned short sM  [128][72];  // [i_local][j] bf16 mask
    __shared__ float sqJ[64];
    __shared__ float cred[128];

    const int tid = threadIdx.x;
    const int w = tid >> 6, l = tid & 63;
    const int l16 = l & 15, lg = l >> 4;
    const int wi = w >> 1, wj = w & 1;        // 2x2 wave grid
    const int itile = blockIdx.x & 63, chunk = blockIdx.x >> 6;
    const int i0 = itile << 7;

    if (tid < 128) cred[tid] = 0.f;

    // hoisted A fragments (x_i hi/lo) + sq_i
    bf16x8 ahi[4][2], alo[4][2];
    float sqi[4][4];
#pragma unroll
    for (int mt = 0; mt < 4; ++mt) {
        int ib = i0 + wi * 64 + mt * 16;
#pragma unroll
        for (int ks = 0; ks < 2; ++ks) {
            size_t off = (size_t)(ib + l16) * 64 + ks * 32 + lg * 8;
            ahi[mt][ks] = *(const bf16x8*)(xhi + off);
            alo[mt][ks] = *(const bf16x8*)(xlo + off);
        }
#pragma unroll
        for (int r = 0; r < 4; ++r) sqi[mt][r] = sq[ib + lg * 4 + r];
    }

    f32x4 accS[4][2];
    float cacc[4][4];
#pragma unroll
    for (int a = 0; a < 4; ++a)
#pragma unroll
        for (int b = 0; b < 2; ++b) {
            accS[a][b][0] = 0.f; accS[a][b][1] = 0.f;
            accS[a][b][2] = 0.f; accS[a][b][3] = 0.f;
        }
#pragma unroll
    for (int a = 0; a < 4; ++a)
#pragma unroll
        for (int r = 0; r < 4; ++r) cacc[a][r] = 0.f;

    const int sj  = (tid & 31) * 2;           // staging: row pair
    const int sd0 = (tid >> 5) * 8;           // staging: d block

    const int jpt = 128 / nchunk;             // j-tiles per chunk
    const int jt0 = chunk * jpt;

    for (int jt = jt0; jt < jt0 + jpt; ++jt) {
        const int j0 = jt << 6;
        // ---- stage x_j tile: rm hi, rm lo, transposed hi, sqJ ----
        uint4 h0 = *(const uint4*)(xhi + (size_t)(j0 + sj) * 64 + sd0);
        uint4 h1 = *(const uint4*)(xhi + (size_t)(j0 + sj + 1) * 64 + sd0);
        uint4 q0 = *(const uint4*)(xlo + (size_t)(j0 + sj) * 64 + sd0);
        uint4 q1 = *(const uint4*)(xlo + (size_t)(j0 + sj + 1) * 64 + sd0);
        *(uint4*)&sJhi[sj][sd0]     = h0;
        *(uint4*)&sJhi[sj + 1][sd0] = h1;
        *(uint4*)&sJlo[sj][sd0]     = q0;
        *(uint4*)&sJlo[sj + 1][sd0] = q1;
        const unsigned short* a0 = (const unsigned short*)&h0;
        const unsigned short* a1 = (const unsigned short*)&h1;
#pragma unroll
        for (int e = 0; e < 8; ++e) {
            unsigned pv = (unsigned)a0[e] | ((unsigned)a1[e] << 16);
            *(unsigned*)&sJT[sd0 + e][sj] = pv;
        }
        if (tid < 64) sqJ[tid] = sq[j0 + tid];
        __syncthreads();

        // ---- dot phase: 64i x 32j per wave, K=64, 3-term split-bf16 ----
        bf16x8 bhi[2][2], blo[2][2];
#pragma unroll
        for (int nt = 0; nt < 2; ++nt)
#pragma unroll
            for (int ks = 0; ks < 2; ++ks) {
                int jr = wj * 32 + nt * 16 + l16;
                bhi[nt][ks] = *(const bf16x8*)&sJhi[jr][ks * 32 + lg * 8];
                blo[nt][ks] = *(const bf16x8*)&sJlo[jr][ks * 32 + lg * 8];
            }
        f32x4 accD[4][2];
#pragma unroll
        for (int a = 0; a < 4; ++a)
#pragma unroll
            for (int b = 0; b < 2; ++b) {
                accD[a][b][0] = 0.f; accD[a][b][1] = 0.f;
                accD[a][b][2] = 0.f; accD[a][b][3] = 0.f;
            }
#pragma unroll
        for (int mt = 0; mt < 4; ++mt)
#pragma unroll
            for (int nt = 0; nt < 2; ++nt)
#pragma unroll
                for (int ks = 0; ks < 2; ++ks) {
                    accD[mt][nt] = MFMA16(ahi[mt][ks], bhi[nt][ks], accD[mt][nt]);
                    accD[mt][nt] = MFMA16(ahi[mt][ks], blo[nt][ks], accD[mt][nt]);
                    accD[mt][nt] = MFMA16(alo[mt][ks], bhi[nt][ks], accD[mt][nt]);
                }

        // ---- threshold -> mask (bf16 0/1) + counts ----
        float sqjv0 = sqJ[wj * 32 + l16];
        float sqjv1 = sqJ[wj * 32 + 16 + l16];
#pragma unroll
        for (int mt = 0; mt < 4; ++mt)
#pragma unroll
            for (int nt = 0; nt < 2; ++nt) {
                float sqj = nt ? sqjv1 : sqjv0;
#pragma unroll
                for (int r = 0; r < 4; ++r) {
                    float d2 = fmaf(accD[mt][nt][r], -2.0f, sqi[mt][r] + sqj);
                    bool in = (d2 <= 121.0f);
                    cacc[mt][r] += in ? 1.0f : 0.0f;
                    sM[wi * 64 + mt * 16 + lg * 4 + r][wj * 32 + nt * 16 + l16] =
                        in ? (unsigned short)0x3F80 : (unsigned short)0;
                }
            }
        __syncthreads();

        // ---- S_ball += mask @ x_hi : 64i x 32d per wave, K(j)=64 ----
        bf16x8 am[4][2], bT[2][2];
#pragma unroll
        for (int mt = 0; mt < 4; ++mt)
#pragma unroll
            for (int ks = 0; ks < 2; ++ks)
                am[mt][ks] = *(const bf16x8*)&sM[wi * 64 + mt * 16 + l16][ks * 32 + lg * 8];
#pragma unroll
        for (int nt = 0; nt < 2; ++nt)
#pragma unroll
            for (int ks = 0; ks < 2; ++ks)
                bT[nt][ks] = *(const bf16x8*)&sJT[wj * 32 + nt * 16 + l16][ks * 32 + lg * 8];
#pragma unroll
        for (int mt = 0; mt < 4; ++mt)
#pragma unroll
            for (int nt = 0; nt < 2; ++nt)
#pragma unroll
                for (int ks = 0; ks < 2; ++ks)
                    accS[mt][nt] = MFMA16(am[mt][ks], bT[nt][ks], accS[mt][nt]);
        __syncthreads();
    }

    // ---- epilogue: counts (reduce over 16 cols-lanes, 2 wj waves) ----
#pragma unroll
    for (int mt = 0; mt < 4; ++mt)
#pragma unroll
        for (int r = 0; r < 4; ++r) {
            float v = cacc[mt][r];
            v += __shfl_xor(v, 1);
            v += __shfl_xor(v, 2);
            v += __shfl_xor(v, 4);
            v += __shfl_xor(v, 8);
            if (l16 == 0) atomicAdd(&cred[wi * 64 + mt * 16 + lg * 4 + r], v);
        }
    __syncthreads();
    if (tid < 128) cpart[(size_t)chunk * NROWS + i0 + tid] = cred[tid];

    // ---- epilogue: S_ball partials ----
#pragma unroll
    for (int mt = 0; mt < 4; ++mt)
#pragma unroll
        for (int nt = 0; nt < 2; ++nt)
#pragma unroll
            for (int r = 0; r < 4; ++r) {
                size_t row = (size_t)chunk * NROWS + i0 + wi * 64 + mt * 16 + lg * 4 + r;
                Spart[row * 64 + wj * 32 + nt * 16 + l16] = accS[mt][nt][r];
            }
}

// ---------------- combine ---------------------------------------------------
__global__ __launch_bounds__(256) void ballq_combine(
        const float* __restrict__ Spart, const float* __restrict__ cpart,
        const float* __restrict__ stot, float* __restrict__ out, int nchunk) {
    int t = blockIdx.x * 256 + threadIdx.x;
    int i = t >> 6, d = t & 63;
    float s = 0.f, c = 0.f;
    for (int ch = 0; ch < nchunk; ++ch) {
        s += Spart[((size_t)ch * NROWS + i) * 64 + d];
        c += cpart[(size_t)ch * NROWS + i];
    }
    const float K = 0.36787944117144233f;     // exp(-1), matches softmax(max-sub)
    float num = s + K * (stot[d] - s);
    float den = c + K * (8192.0f - c);
    out[t] = num / den;
}

extern "C" void kernel_launch(void* const* d_in, const int* in_sizes, int n_in,
                              void* d_out, int out_size, void* d_ws, size_t ws_size,
                              hipStream_t stream) {
    (void)in_sizes; (void)n_in; (void)out_size;
    const float* x = (const float*)d_in[0];
    float* out = (float*)d_out;
    char* ws = (char*)d_ws;

    unsigned short* xhi = (unsigned short*)ws;                 // 1 MB
    unsigned short* xlo = (unsigned short*)(ws + (1u << 20));  // 1 MB
    float* sq   = (float*)(ws + (2u << 20));                   // 32 KB
    float* stot = (float*)(ws + (2u << 20) + 32768);           // 256 B
    size_t fixed = (2u << 20) + 32768 + 256;
    char* dyn = ws + fixed;

    int nchunk = 8;
    while (nchunk > 1 &&
           fixed + (size_t)nchunk * NROWS * 4 + (size_t)nchunk * NROWS * 64 * 4 > ws_size)
        nchunk >>= 1;
    float* cpart = (float*)dyn;
    float* Spart = (float*)(dyn + (size_t)nchunk * NROWS * 4);

    hipMemsetAsync(stot, 0, 256, stream);
    prep_hilo<<<512, 256, 0, stream>>>(x, xhi, xlo, sq);
    prep_coltot<<<64, 256, 0, stream>>>(x, stot);
    ballq_main<<<64 * nchunk, 256, 0, stream>>>(xhi, xlo, sq, Spart, cpart, nchunk);
    ballq_combine<<<2048, 256, 0, stream>>>(Spart, cpart, stot, out, nchunk);
}